// Round 8
// baseline (277.422 us; speedup 1.0000x reference)
//
#include <hip/hip_runtime.h>
#include <hip/hip_bf16.h>

// Problem constants
#define NB 2
#define SEQ 2048
#define HEADS 16
#define HD 64
#define ED 1024

typedef __bf16 bf16x8 __attribute__((ext_vector_type(8)));
typedef float f32x4 __attribute__((ext_vector_type(4)));
typedef unsigned short u16x8 __attribute__((ext_vector_type(8)));
typedef unsigned short u16x4 __attribute__((ext_vector_type(4)));

__device__ __forceinline__ unsigned short f2bf(float f) {
    unsigned u = __builtin_bit_cast(unsigned, f);
    u += 0x7fffu + ((u >> 16) & 1u);   // RNE
    return (unsigned short)(u >> 16);
}

__device__ __forceinline__ bf16x8 cvt8(const float* __restrict__ p) {
    const float4* p4 = (const float4*)p;
    float4 a = p4[0], b = p4[1];
    u16x8 u;
    u[0] = f2bf(a.x); u[1] = f2bf(a.y); u[2] = f2bf(a.z); u[3] = f2bf(a.w);
    u[4] = f2bf(b.x); u[5] = f2bf(b.y); u[6] = f2bf(b.z); u[7] = f2bf(b.w);
    return __builtin_bit_cast(bf16x8, u);
}

__device__ __forceinline__ bf16x8 ldfrag(const void* p) {
    uint4 v = *(const uint4*)p;
    return __builtin_bit_cast(bf16x8, v);
}

__device__ __forceinline__ f32x4 mfma16(bf16x8 a, bf16x8 b, f32x4 c) {
    return __builtin_amdgcn_mfma_f32_16x16x32_bf16(a, b, c, 0, 0, 0);
}

// pack two positive f32 into bf16 pair (round-half-up): 2 adds + v_perm
__device__ __forceinline__ unsigned packbf(float lo, float hi) {
    unsigned a = __builtin_bit_cast(unsigned, hi) + 0x8000u;
    unsigned b = __builtin_bit_cast(unsigned, lo) + 0x8000u;
    return __builtin_amdgcn_perm(a, b, 0x07060302u);   // [hi16(a) : hi16(b)]
}

// combine two bf16 pairs (as dwords) with scale -> bf16 pair
__device__ __forceinline__ unsigned comb2(unsigned d0, unsigned d1, float rl) {
    float lo = (__builtin_bit_cast(float, d0 << 16) +
                __builtin_bit_cast(float, d1 << 16)) * rl;
    float hi = (__builtin_bit_cast(float, d0 & 0xffff0000u) +
                __builtin_bit_cast(float, d1 & 0xffff0000u)) * rl;
    return packbf(lo, hi);
}

#define GLOAD_LDS(gp, lp) \
    __builtin_amdgcn_global_load_lds( \
        (const __attribute__((address_space(1))) unsigned int*)(gp), \
        (__attribute__((address_space(3))) unsigned int*)(lp), 16, 0, 0)

// softmax scale folded into Q at projection: (1/sqrt(1024)) * log2(e)
#define QSCALE 0.04508422f

// ---------------- kernel: mask->bits  +  Wo fp32->bf16 (merged) ------------
__global__ __launch_bounds__(256) void prep_kernel(
    const int* __restrict__ mask, unsigned long long* __restrict__ bits,
    const float* __restrict__ Wo, unsigned short* __restrict__ Wob)
{
    int bid = blockIdx.x;
    if (bid < NB * SEQ * SEQ / 256) {
        size_t i = (size_t)bid * 256 + threadIdx.x;
        int m = mask[i];
        unsigned long long b = __ballot(m != 0);
        if ((threadIdx.x & 63) == 0) bits[i >> 6] = b;
    } else {
        size_t i = ((size_t)(bid - NB * SEQ * SEQ / 256) * 256 + threadIdx.x) * 4;
        float4 v = *(const float4*)(Wo + i);
        u16x4 u;
        u[0] = f2bf(v.x); u[1] = f2bf(v.y); u[2] = f2bf(v.z); u[3] = f2bf(v.w);
        *(u16x4*)(Wob + i) = u;
    }
}

// ---------------- kernel: QKV head projections via MFMA --------------------
// Q,K stored [n][h][s][64] bf16 (Q pre-scaled by QSCALE);
// V stored tiled [n][h][s/64][d][64] bf16.
__global__ __launch_bounds__(256) void proj_kernel(
    const float* __restrict__ qin, const float* __restrict__ kin, const float* __restrict__ vin,
    const float* __restrict__ Wq, const float* __restrict__ Wk, const float* __restrict__ Wv,
    unsigned short* __restrict__ Qb, unsigned short* __restrict__ Kb,
    unsigned short* __restrict__ Vt)
{
    __shared__ __align__(16) char tile[64 * 144];   // 64 rows x 144B (128B data + pad)

    int t3  = blockIdx.x >> 10;
    int rem = blockIdx.x & 1023;
    int h   = rem >> 6;
    int rt  = rem & 63;
    int wave = threadIdx.x >> 6, lane = threadIdx.x & 63;
    int quad = lane >> 4, l16 = lane & 15;

    const float* in = (t3 == 0) ? qin : ((t3 == 1) ? kin : vin);
    const float* W  = (t3 == 0) ? Wq  : ((t3 == 1) ? Wk  : Wv);

    int r0 = rt * 64 + wave * 16;   // global token row base for this wave

    bf16x8 bf0[4], bf1[4];
#pragma unroll
    for (int sl = 0; sl < 4; ++sl) {
        const float* wrow = W + (sl * 16 + l16) * 64;
        bf0[sl] = cvt8(wrow + quad * 8);
        bf1[sl] = cvt8(wrow + 32 + quad * 8);
    }
    const float* xrow = in + (size_t)(r0 + l16) * ED + h * 64;
    bf16x8 af0 = cvt8(xrow + quad * 8);
    bf16x8 af1 = cvt8(xrow + 32 + quad * 8);

    f32x4 acc[4];
#pragma unroll
    for (int sl = 0; sl < 4; ++sl) {
        f32x4 c = {0.f, 0.f, 0.f, 0.f};
        c = mfma16(af0, bf0[sl], c);
        c = mfma16(af1, bf1[sl], c);
        acc[sl] = c;
    }
    float sc = (t3 == 0) ? QSCALE : 1.0f;

    size_t nh = (size_t)((r0 >> 11) * HEADS + h);   // 64-row tile never straddles n
    int rl = lane >> 3, cl = lane & 7;              // readback row-in-group / 16B slot

    if (t3 != 2) {
        // ---- Q/K: LDS tile [s_local][e], wave-private rows, no barrier -----
#pragma unroll
        for (int r = 0; r < 4; ++r) {
            int srow = wave * 16 + quad * 4 + r;
#pragma unroll
            for (int sl = 0; sl < 4; ++sl)
                *(unsigned short*)(tile + srow * 144 + (sl * 16 + l16) * 2) =
                    f2bf(acc[sl][r] * sc);
        }
        unsigned short* dst = (t3 == 0) ? Qb : Kb;
        int s0 = (r0 & 2047);                        // this wave's first token row
#pragma unroll
        for (int g = 0; g < 2; ++g) {
            int lrow = wave * 16 + g * 8 + rl;
            uint4 v = *(const uint4*)(tile + lrow * 144 + cl * 16);
            *(uint4*)(dst + (nh * SEQ + (s0 & ~15) + g * 8 + rl) * HD + cl * 8) = v;
        }
    } else {
        // ---- V: LDS tile [e][s_local] (transpose), barrier across waves ----
#pragma unroll
        for (int r = 0; r < 4; ++r) {
            int srow = wave * 16 + quad * 4 + r;
#pragma unroll
            for (int sl = 0; sl < 4; ++sl)
                *(unsigned short*)(tile + (sl * 16 + l16) * 144 + srow * 2) =
                    f2bf(acc[sl][r]);
        }
        __syncthreads();
        int s_tile = rt & 31;
#pragma unroll
        for (int g = 0; g < 2; ++g) {
            int erow = wave * 16 + g * 8 + rl;
            uint4 v = *(const uint4*)(tile + erow * 144 + cl * 16);
            *(uint4*)(Vt + ((nh * 32 + s_tile) * 64 + erow) * 64 + cl * 8) = v;
        }
    }
}

// ---------------- kernel: flash attention, single-barrier pipeline ---------
// 256 threads = 4 waves x 32 queries = 128 q / block.
// K AND V double-buffered; K_{i+1},V_{i+1} prefetched right after the one
// barrier -> full-iteration lead, one rendezvous per iter.
// P region: stride-128 with XOR rotation (write unit (kt*2+q2)^r8,
// read unit (quad+4kk)^r8), wave-private, in-wave DS ordering.
// SPLIT=1: grid 1024 (2 k-halves), partial bf16 O + f32 lsum out; else 512.
template <int SPLIT>
__global__ __launch_bounds__(256, 4) void attn_kernel(
    const unsigned short* __restrict__ Qb, const unsigned short* __restrict__ Kb,
    const unsigned short* __restrict__ Vt2, const unsigned long long* __restrict__ mb,
    unsigned short* __restrict__ Ab, unsigned short* __restrict__ Of,
    float* __restrict__ Ls)
{
    // K dbuf 2x8K @0, V dbuf 2x8K @16384, P 4x2K @32768  => 40960 B
    __shared__ __align__(16) char smem[40960];

    int tid = threadIdx.x;
    int wave = tid >> 6, lane = tid & 63;
    int quad = lane >> 4, l16 = lane & 15;

    // XCD swizzle: 4 consecutive nh per XCD -> K/V resident in its L2
    int b   = blockIdx.x;
    int xcd = b & 7;
    int j   = b >> 3;
    int nh, qb, half;
    if (SPLIT) { nh = xcd * 4 + (j >> 5); int r = j & 31; qb = r >> 1; half = r & 1; }
    else       { nh = xcd * 4 + (j >> 4); qb = j & 15; half = 0; }
    int n = nh >> 4, h = nh & 15;
    int q0 = qb * 128 + wave * 32;          // this wave's 32 queries

    size_t headoff = (size_t)nh * SEQ * HD;
    bf16x8 qf[2][2];                         // B-operand
#pragma unroll
    for (int t = 0; t < 2; ++t) {
        const unsigned short* qrow = Qb + headoff + (size_t)(q0 + t * 16 + l16) * HD;
        qf[t][0] = ldfrag(qrow + quad * 8);
        qf[t][1] = ldfrag(qrow + 32 + quad * 8);
    }

    // staging: per-lane source offset (bytes) with rotation ((slot - row)&7)
    int srow = lane >> 3, sslot = lane & 7;
    int stoff = srow * 128 + (((sslot - srow) & 7) * 16);

    // K/V ds read addrs (loop-invariant)
    int rotA = ((quad + l16) & 7) * 16;
    int aK  = l16 * 128 + rotA;           // + par*8192 + kt*2048 ; ^64 high half
    int aV  = l16 * 128 + rotA;           // + 16384 + par*8192 + sl*2048 ; ^64

    // P addrs: XOR-rotated stride-128, wave-private 2 KB
    int r8 = l16 & 7, q1 = quad & 1, q2 = quad >> 1;
    char* pP = smem + 32768 + wave * 2048;
    int pwoff = l16 * 128 + q1 * 8 + ((q2 ^ (r8 & 1)) * 16) + ((r8 & 6) * 16); // ^ kt*32
    int proff = l16 * 128 + ((quad ^ r8) * 16);                                // ^ kk*64

    const unsigned short* gK = Kb + headoff;
    const unsigned short* gV = Vt2 + (size_t)nh * (32 * 4096);
    const unsigned long long* mbase = mb + (size_t)n * (SEQ * SEQ / 64)
                                         + (size_t)(q0 + l16) * (SEQ / 64);

    // all-ones bf16 A-fragment for row sums
    u16x8 ou;
#pragma unroll
    for (int jj = 0; jj < 8; ++jj) ou[jj] = 0x3F80;
    bf16x8 ones = __builtin_bit_cast(bf16x8, ou);

    f32x4 o[2][4] = {{{0,0,0,0},{0,0,0,0},{0,0,0,0},{0,0,0,0}},
                     {{0,0,0,0},{0,0,0,0},{0,0,0,0},{0,0,0,0}}};
    f32x4 lacc[2] = {{0,0,0,0},{0,0,0,0}};
    int qsh = quad * 4;

    int kb0   = SPLIT ? half * (SEQ / 2) : 0;
    int kbend = SPLIT ? kb0 + (SEQ / 2) : SEQ;

    // ---- prologue: stage K_0, V_0 into parity-0 buffers --------------------
    {
        const char* sK = (const char*)(gK + (size_t)kb0 * 64) + stoff;
        const char* sV = (const char*)(gV + (size_t)(kb0 >> 6) * 4096) + stoff;
#pragma unroll
        for (int i2 = 0; i2 < 2; ++i2) {
            int c = wave * 2 + i2;
            GLOAD_LDS(sK + c * 1024, smem + c * 1024);
            GLOAD_LDS(sV + c * 1024, smem + 16384 + c * 1024);
        }
    }

    int par = 0;
    for (int kb = kb0; kb < kbend; kb += 64) {
        int kbn = (kb + 64) & (SEQ - 1);   // wrapped next tile (harmless at end)
        __syncthreads();   // K_i,V_i visible (full-iter lead); prev reads done
        // ---- prefetch K_{i+1}, V_{i+1} into parity^1 buffers ---------------
        {
            const char* nK = (const char*)(gK + (size_t)kbn * 64) + stoff;
            const char* nV = (const char*)(gV + (size_t)(kbn >> 6) * 4096) + stoff;
            int pb8 = (par ^ 1) * 8192;
#pragma unroll
            for (int i2 = 0; i2 < 2; ++i2) {
                int c = wave * 2 + i2;
                GLOAD_LDS(nK + c * 1024, smem + pb8 + c * 1024);
                GLOAD_LDS(nV + c * 1024, smem + 16384 + pb8 + c * 1024);
            }
        }
        // mask rows (L2-hot), pre-shifted by quad
        unsigned long long m64[2];
#pragma unroll
        for (int t = 0; t < 2; ++t)
            m64[t] = mbase[(size_t)(t * 16) * (SEQ / 64) + (kb >> 6)] >> qsh;

        // ---- K fragments (A-operand) from current parity buffer ------------
        const char* kbuf = smem + par * 8192;
        const char* vbuf = smem + 16384 + par * 8192;
        bf16x8 kf[4][2];
#pragma unroll
        for (int kt = 0; kt < 4; ++kt) {
            kf[kt][0] = ldfrag(kbuf + (aK + kt * 2048));
            kf[kt][1] = ldfrag(kbuf + ((aK ^ 64) + kt * 2048));
        }
        // ---- per q-subtile: S^T=K*Q^T, mask+exp, P round-trip, sums, PV ----
#pragma unroll
        for (int t = 0; t < 2; ++t) {
            f32x4 c[4];
#pragma unroll
            for (int kt = 0; kt < 4; ++kt) {
                f32x4 cc = {0.f, 0.f, 0.f, 0.f};
                cc = mfma16(kf[kt][0], qf[t][0], cc);
                cc = mfma16(kf[kt][1], qf[t][1], cc);
                c[kt] = cc;   // c[kt][r]: key = kb+kt*16+quad*4+r, q = q0+t*16+l16
            }
            unsigned mlo = (unsigned)m64[t];
            unsigned mhi = (unsigned)(m64[t] >> 32);
#pragma unroll
            for (int kt = 0; kt < 4; ++kt) {
                unsigned mw = (kt & 2) ? mhi : mlo;
                int bs = (kt & 1) ? 16 : 0;
                float p0 = ((mw >> (bs + 0)) & 1u) ? __builtin_exp2f(c[kt][0]) : 0.f;
                float p1 = ((mw >> (bs + 1)) & 1u) ? __builtin_exp2f(c[kt][1]) : 0.f;
                float p2 = ((mw >> (bs + 2)) & 1u) ? __builtin_exp2f(c[kt][2]) : 0.f;
                float p3 = ((mw >> (bs + 3)) & 1u) ? __builtin_exp2f(c[kt][3]) : 0.f;
                uint2 dw = { packbf(p0, p1), packbf(p2, p3) };
                *(uint2*)(pP + (pwoff ^ (kt * 32))) = dw;
            }
            // P^T B-fragments (in-wave write->read ordering via DS pipe)
            bf16x8 pb0 = ldfrag(pP + proff);
            bf16x8 pb1 = ldfrag(pP + (proff ^ 64));
            // row sums on the matrix pipe (quad-uniform result)
            lacc[t] = mfma16(ones, pb0, lacc[t]);
            lacc[t] = mfma16(ones, pb1, lacc[t]);
            // O^T = V^T * P^T
#pragma unroll
            for (int sl = 0; sl < 4; ++sl) {
                o[t][sl] = mfma16(ldfrag(vbuf + (aV + sl * 2048)), pb0, o[t][sl]);
                o[t][sl] = mfma16(ldfrag(vbuf + ((aV ^ 64) + sl * 2048)), pb1, o[t][sl]);
            }
        }
        par ^= 1;
    }

    // ---- epilogue: o[t][sl][r] = O[q=q0+t*16+l16][d=sl*16+quad*4+r] --------
#pragma unroll
    for (int t = 0; t < 2; ++t) {
        float s = lacc[t][0];               // row-sum, uniform across quads
        int q = q0 + t * 16 + l16;
        if (SPLIT) {
            size_t qg = (size_t)nh * SEQ + q;
            if (quad == 0) Ls[(size_t)half * 65536 + qg] = s;
            // partial O in bf16: [half][nh][s][64]
            unsigned short* op = Of + ((size_t)half * 32 * SEQ + qg) * 64 + qsh;
#pragma unroll
            for (int sl = 0; sl < 4; ++sl) {
                uint2 dw = { packbf(o[t][sl][0], o[t][sl][1]),
                             packbf(o[t][sl][2], o[t][sl][3]) };
                *(uint2*)(op + sl * 16) = dw;
            }
        } else {
            float rinv = 1.0f / s;
            unsigned short* op = Ab + (((size_t)(n * SEQ + q)) * HEADS + h) * HD + qsh;
#pragma unroll
            for (int sl = 0; sl < 4; ++sl) {
                u16x4 u;
                u[0] = f2bf(o[t][sl][0] * rinv);
                u[1] = f2bf(o[t][sl][1] * rinv);
                u[2] = f2bf(o[t][sl][2] * rinv);
                u[3] = f2bf(o[t][sl][3] * rinv);
                *(u16x4*)(op + sl * 16) = u;
            }
        }
    }
}

// ---------------- kernel: out = Attn @ Wo^T + bo (combine fused) -----------
// grid 256 = 32 row-tiles x 8 col-tiles of 128x128; 4 waves, each 64x64.
// FUSED=1: A-tile built from Of halves + Ls (combine inline, ds_write_b128
// with the same additive rotation the reads expect). FUSED=0: GLOAD from Ab.
template <int FUSED>
__global__ __launch_bounds__(256) void out_gemm_kernel(
    const unsigned short* __restrict__ Ab, const unsigned short* __restrict__ Of,
    const float* __restrict__ Ls, const unsigned short* __restrict__ Wob,
    const float* __restrict__ bo, float* __restrict__ out)
{
    __shared__ __align__(16) char lds[32768];    // At 16KB + Bt 16KB (BK=64)

    int tid = threadIdx.x;
    int wave = tid >> 6, lane = tid & 63;
    int quad = lane >> 4, l16 = lane & 15;
    int rt = blockIdx.x >> 3, ct = blockIdx.x & 7;
    int wr = wave >> 1, wc = wave & 1;

    int srow = lane >> 3, sslot = lane & 7;
    int stoff = srow * 2048 + (((sslot - srow) & 7) * 16);
    const char* gA = (const char*)Ab  + (size_t)rt * 128 * 2048 + stoff;
    const char* gB = (const char*)Wob + (size_t)ct * 128 * 2048 + stoff;

    int nbase = (rt >> 4) * 16;        // n*16 (128-token tiles never straddle n)
    int sb    = (rt & 15) * 128;       // first token s within n
    int r0l = tid >> 3, slot = tid & 7;   // fused staging: row group / 16B slot

    int aA[4], aB[4];
#pragma unroll
    for (int i = 0; i < 4; ++i) {
        int rowA = wr * 64 + i * 16 + l16;
        aA[i] = rowA * 128 + (((quad + rowA) & 7) * 16);
        int rowB = wc * 64 + i * 16 + l16;
        aB[i] = 16384 + rowB * 128 + (((quad + rowB) & 7) * 16);
    }

    f32x4 acc[4][4] = {};
    for (int f = 0; f < ED; f += 64) {
        __syncthreads();
        if (FUSED) {
            // ---- A-tile: combine Of halves for head hf = f>>6 --------------
            int nh2 = nbase + (f >> 6);
            const unsigned short* of0 = Of + ((size_t)nh2 * SEQ + sb) * 64;
            const unsigned short* of1 = of0 + (size_t)32 * SEQ * 64;
            const float* ls0 = Ls + (size_t)nh2 * SEQ + sb;
#pragma unroll
            for (int k = 0; k < 4; ++k) {
                int row = r0l + k * 32;
                uint4 a0 = *(const uint4*)(of0 + (size_t)row * 64 + slot * 8);
                uint4 a1 = *(const uint4*)(of1 + (size_t)row * 64 + slot * 8);
                float rl = 1.0f / (ls0[row] + ls0[65536 + row]);
                uint4 w;
                w.x = comb2(a0.x, a1.x, rl);
                w.y = comb2(a0.y, a1.y, rl);
                w.z = comb2(a0.z, a1.z, rl);
                w.w = comb2(a0.w, a1.w, rl);
                *(uint4*)(lds + row * 128 + (((slot + row) & 7) * 16)) = w;
            }
            // ---- B-tile via GLOAD ------------------------------------------
#pragma unroll
            for (int i = 0; i < 4; ++i) {
                int c = wave * 4 + i;
                GLOAD_LDS(gB + (size_t)c * 16384 + f * 2, lds + 16384 + c * 1024);
            }
        } else {
#pragma unroll
            for (int i = 0; i < 4; ++i) {
                int c = wave * 4 + i;
                GLOAD_LDS(gA + (size_t)c * 16384 + f * 2, lds + c * 1024);
                GLOAD_LDS(gB + (size_t)c * 16384 + f * 2, lds + 16384 + c * 1024);
            }
        }
        __syncthreads();
#pragma unroll
        for (int kk = 0; kk < 2; ++kk) {
            int x = kk * 64;
            bf16x8 af[4], bfr[4];
#pragma unroll
            for (int i = 0; i < 4; ++i)  af[i]  = ldfrag(lds + (aA[i] ^ x));
#pragma unroll
            for (int sl = 0; sl < 4; ++sl) bfr[sl] = ldfrag(lds + (aB[sl] ^ x));
#pragma unroll
            for (int i = 0; i < 4; ++i)
#pragma unroll
                for (int sl = 0; sl < 4; ++sl)
                    acc[i][sl] = mfma16(af[i], bfr[sl], acc[i][sl]);
        }
    }

    float bv[4];
#pragma unroll
    for (int sl = 0; sl < 4; ++sl)
        bv[sl] = bo[ct * 128 + wc * 64 + sl * 16 + l16];
#pragma unroll
    for (int i = 0; i < 4; ++i)
#pragma unroll
        for (int r = 0; r < 4; ++r) {
            int row = rt * 128 + wr * 64 + i * 16 + quad * 4 + r;
#pragma unroll
            for (int sl = 0; sl < 4; ++sl) {
                int e = ct * 128 + wc * 64 + sl * 16 + l16;
                out[(size_t)row * ED + e] = acc[i][sl][r] + bv[sl];
            }
        }
}

// ---------------- launcher -------------------------------------------------
extern "C" void kernel_launch(void* const* d_in, const int* in_sizes, int n_in,
                              void* d_out, int out_size, void* d_ws, size_t ws_size,
                              hipStream_t stream)
{
    const float* values = (const float*)d_in[0];
    const float* keys   = (const float*)d_in[1];
    const float* query  = (const float*)d_in[2];
    const int*   mask   = (const int*)d_in[3];
    const float* Wv     = (const float*)d_in[4];
    const float* Wk     = (const float*)d_in[5];
    const float* Wq     = (const float*)d_in[6];
    const float* Wo     = (const float*)d_in[7];
    const float* bo     = (const float*)d_in[8];
    float* out = (float*)d_out;

    char* w = (char*)d_ws;
    unsigned short* Qb  = (unsigned short*)(w);              //  8 MB
    unsigned short* Kb  = (unsigned short*)(w +  8388608);   //  8 MB
    unsigned short* Vt  = (unsigned short*)(w + 16777216);   //  8 MB tiled V
    unsigned short* Ab  = (unsigned short*)(w + 25165824);   //  8 MB (non-split)
    unsigned long long* Mb = (unsigned long long*)(w + 33554432); // 1 MB
    unsigned short* Wob = (unsigned short*)(w + 34603008);   //  2 MB
    unsigned short* Of  = (unsigned short*)(w + 36700160);   // 16.8 MB bf16 (split)
    float* Ls = (float*)(w + 53477376);                      // 0.5 MB f32 (split)

    bool split = ws_size >= 54001664ULL;

    prep_kernel<<<NB * SEQ * SEQ / 256 + ED * ED / 1024, 256, 0, stream>>>(mask, Mb, Wo, Wob);
    proj_kernel<<<3 * HEADS * 64, 256, 0, stream>>>(query, keys, values, Wq, Wk, Wv, Qb, Kb, Vt);
    if (split) {
        attn_kernel<1><<<1024, 256, 0, stream>>>(Qb, Kb, Vt, Mb, Ab, Of, Ls);
        out_gemm_kernel<1><<<256, 256, 0, stream>>>(Ab, Of, Ls, Wob, bo, out);
    } else {
        attn_kernel<0><<<512, 256, 0, stream>>>(Qb, Kb, Vt, Mb, Ab, Of, Ls);
        out_gemm_kernel<0><<<256, 256, 0, stream>>>(Ab, Of, Ls, Wob, bo, out);
    }
}

// Round 10
// 243.945 us; speedup vs baseline: 1.1372x; 1.1372x over previous
//
#include <hip/hip_runtime.h>
#include <hip/hip_bf16.h>

// Problem constants
#define NB 2
#define SEQ 2048
#define HEADS 16
#define HD 64
#define ED 1024

typedef __bf16 bf16x8 __attribute__((ext_vector_type(8)));
typedef float f32x4 __attribute__((ext_vector_type(4)));
typedef unsigned short u16x8 __attribute__((ext_vector_type(8)));
typedef unsigned short u16x4 __attribute__((ext_vector_type(4)));

__device__ __forceinline__ unsigned short f2bf(float f) {
    unsigned u = __builtin_bit_cast(unsigned, f);
    u += 0x7fffu + ((u >> 16) & 1u);   // RNE
    return (unsigned short)(u >> 16);
}

__device__ __forceinline__ bf16x8 cvt8(const float* __restrict__ p) {
    const float4* p4 = (const float4*)p;
    float4 a = p4[0], b = p4[1];
    u16x8 u;
    u[0] = f2bf(a.x); u[1] = f2bf(a.y); u[2] = f2bf(a.z); u[3] = f2bf(a.w);
    u[4] = f2bf(b.x); u[5] = f2bf(b.y); u[6] = f2bf(b.z); u[7] = f2bf(b.w);
    return __builtin_bit_cast(bf16x8, u);
}

__device__ __forceinline__ bf16x8 ldfrag(const void* p) {
    uint4 v = *(const uint4*)p;
    return __builtin_bit_cast(bf16x8, v);
}

__device__ __forceinline__ f32x4 mfma16(bf16x8 a, bf16x8 b, f32x4 c) {
    return __builtin_amdgcn_mfma_f32_16x16x32_bf16(a, b, c, 0, 0, 0);
}

// pack two positive f32 into bf16 pair (round-half-up): 2 adds + v_perm
__device__ __forceinline__ unsigned packbf(float lo, float hi) {
    unsigned a = __builtin_bit_cast(unsigned, hi) + 0x8000u;
    unsigned b = __builtin_bit_cast(unsigned, lo) + 0x8000u;
    return __builtin_amdgcn_perm(a, b, 0x07060302u);   // [hi16(a) : hi16(b)]
}

#define GLOAD_LDS(gp, lp) \
    __builtin_amdgcn_global_load_lds( \
        (const __attribute__((address_space(1))) unsigned int*)(gp), \
        (__attribute__((address_space(3))) unsigned int*)(lp), 16, 0, 0)

// softmax scale folded into Q at projection: (1/sqrt(1024)) * log2(e)
#define QSCALE 0.04508422f

// ---------------- kernel: mask->bits  +  Wo fp32->bf16 (merged) ------------
__global__ __launch_bounds__(256) void prep_kernel(
    const int* __restrict__ mask, unsigned long long* __restrict__ bits,
    const float* __restrict__ Wo, unsigned short* __restrict__ Wob)
{
    int bid = blockIdx.x;
    if (bid < NB * SEQ * SEQ / 256) {
        size_t i = (size_t)bid * 256 + threadIdx.x;
        int m = mask[i];
        unsigned long long b = __ballot(m != 0);
        if ((threadIdx.x & 63) == 0) bits[i >> 6] = b;
    } else {
        size_t i = ((size_t)(bid - NB * SEQ * SEQ / 256) * 256 + threadIdx.x) * 4;
        float4 v = *(const float4*)(Wo + i);
        u16x4 u;
        u[0] = f2bf(v.x); u[1] = f2bf(v.y); u[2] = f2bf(v.z); u[3] = f2bf(v.w);
        *(u16x4*)(Wob + i) = u;
    }
}

// ---------------- kernel: QKV head projections via MFMA --------------------
// Q,K stored [n][h][s][64] bf16 (Q pre-scaled by QSCALE);
// V stored tiled [n][h][s/64][d][64] bf16.
__global__ __launch_bounds__(256) void proj_kernel(
    const float* __restrict__ qin, const float* __restrict__ kin, const float* __restrict__ vin,
    const float* __restrict__ Wq, const float* __restrict__ Wk, const float* __restrict__ Wv,
    unsigned short* __restrict__ Qb, unsigned short* __restrict__ Kb,
    unsigned short* __restrict__ Vt)
{
    __shared__ __align__(16) char tile[64 * 144];   // 64 rows x 144B (128B data + pad)

    int t3  = blockIdx.x >> 10;
    int rem = blockIdx.x & 1023;
    int h   = rem >> 6;
    int rt  = rem & 63;
    int wave = threadIdx.x >> 6, lane = threadIdx.x & 63;
    int quad = lane >> 4, l16 = lane & 15;

    const float* in = (t3 == 0) ? qin : ((t3 == 1) ? kin : vin);
    const float* W  = (t3 == 0) ? Wq  : ((t3 == 1) ? Wk  : Wv);

    int r0 = rt * 64 + wave * 16;   // global token row base for this wave

    bf16x8 bf0[4], bf1[4];
#pragma unroll
    for (int sl = 0; sl < 4; ++sl) {
        const float* wrow = W + (sl * 16 + l16) * 64;
        bf0[sl] = cvt8(wrow + quad * 8);
        bf1[sl] = cvt8(wrow + 32 + quad * 8);
    }
    const float* xrow = in + (size_t)(r0 + l16) * ED + h * 64;
    bf16x8 af0 = cvt8(xrow + quad * 8);
    bf16x8 af1 = cvt8(xrow + 32 + quad * 8);

    f32x4 acc[4];
#pragma unroll
    for (int sl = 0; sl < 4; ++sl) {
        f32x4 c = {0.f, 0.f, 0.f, 0.f};
        c = mfma16(af0, bf0[sl], c);
        c = mfma16(af1, bf1[sl], c);
        acc[sl] = c;
    }
    float sc = (t3 == 0) ? QSCALE : 1.0f;

    size_t nh = (size_t)((r0 >> 11) * HEADS + h);   // 64-row tile never straddles n
    int rl = lane >> 3, cl = lane & 7;              // readback row-in-group / 16B slot

    if (t3 != 2) {
        // ---- Q/K: LDS tile [s_local][e], wave-private rows, no barrier -----
#pragma unroll
        for (int r = 0; r < 4; ++r) {
            int srow = wave * 16 + quad * 4 + r;
#pragma unroll
            for (int sl = 0; sl < 4; ++sl)
                *(unsigned short*)(tile + srow * 144 + (sl * 16 + l16) * 2) =
                    f2bf(acc[sl][r] * sc);
        }
        unsigned short* dst = (t3 == 0) ? Qb : Kb;
        int s0 = (r0 & 2047);                        // this wave's first token row
#pragma unroll
        for (int g = 0; g < 2; ++g) {
            int lrow = wave * 16 + g * 8 + rl;
            uint4 v = *(const uint4*)(tile + lrow * 144 + cl * 16);
            *(uint4*)(dst + (nh * SEQ + (s0 & ~15) + g * 8 + rl) * HD + cl * 8) = v;
        }
    } else {
        // ---- V: LDS tile [e][s_local] (transpose), barrier across waves ----
#pragma unroll
        for (int r = 0; r < 4; ++r) {
            int srow = wave * 16 + quad * 4 + r;
#pragma unroll
            for (int sl = 0; sl < 4; ++sl)
                *(unsigned short*)(tile + (sl * 16 + l16) * 144 + srow * 2) =
                    f2bf(acc[sl][r]);
        }
        __syncthreads();
        int s_tile = rt & 31;
#pragma unroll
        for (int g = 0; g < 2; ++g) {
            int erow = wave * 16 + g * 8 + rl;
            uint4 v = *(const uint4*)(tile + erow * 144 + cl * 16);
            *(uint4*)(Vt + ((nh * 32 + s_tile) * 64 + erow) * 64 + cl * 8) = v;
        }
    }
}

// ---------------- kernel: flash attention (R7 two-barrier pipeline) --------
// 256 threads = 4 waves x 32 queries = 128 q / block.
// K double-buffered, V single-buffered; K prefetch after barrier (a), V
// prefetch after barrier (b) -> every staging load has >=0.7-iter lead.
// S^T scheme (A=K, B=Q); P round-trip via per-wave LDS tile; row-sums via
// all-ones MFMA (quad-uniform -> no shuffle reduction).
// SPLIT=1: grid 1024 (2 k-halves), partial f32 O + lsum out; else grid 512.
template <int SPLIT>
__global__ __launch_bounds__(256, 4) void attn_kernel(
    const unsigned short* __restrict__ Qb, const unsigned short* __restrict__ Kb,
    const unsigned short* __restrict__ Vt2, const unsigned long long* __restrict__ mb,
    unsigned short* __restrict__ Ab, float* __restrict__ Of, float* __restrict__ Ls)
{
    // K buf0 @0, K buf1 @8192, V @16384, P @24576 + wave*2304
    __shared__ __align__(16) char smem[24576 + 4 * 2304];

    int tid = threadIdx.x;
    int wave = tid >> 6, lane = tid & 63;
    int quad = lane >> 4, l16 = lane & 15;

    // XCD swizzle: 4 consecutive nh per XCD -> K/V resident in its L2
    int b   = blockIdx.x;
    int xcd = b & 7;
    int j   = b >> 3;
    int nh, qb, half;
    if (SPLIT) { nh = xcd * 4 + (j >> 5); int r = j & 31; qb = r >> 1; half = r & 1; }
    else       { nh = xcd * 4 + (j >> 4); qb = j & 15; half = 0; }
    int n = nh >> 4, h = nh & 15;
    int q0 = qb * 128 + wave * 32;          // this wave's 32 queries

    size_t headoff = (size_t)nh * SEQ * HD;
    bf16x8 qf[2][2];                         // B-operand
#pragma unroll
    for (int t = 0; t < 2; ++t) {
        const unsigned short* qrow = Qb + headoff + (size_t)(q0 + t * 16 + l16) * HD;
        qf[t][0] = ldfrag(qrow + quad * 8);
        qf[t][1] = ldfrag(qrow + 32 + quad * 8);
    }

    // staging: per-lane source offset (bytes) with rotation ((slot - row)&7)
    int srow = lane >> 3, sslot = lane & 7;
    int stoff = srow * 128 + (((sslot - srow) & 7) * 16);

    // ds read address registers (bytes, loop-invariant)
    int rotA = ((quad + l16) & 7) * 16;
    int aK0 = l16 * 128 + rotA;           // + par*8192 + kt*2048 ; ^64 high half
    int aV  = 16384 + l16 * 128 + rotA;   // + sl*2048 ; ^64 key high half
    int aVx = aV ^ 64;
    char* pbase = smem + 24576 + wave * 2304;   // shared across t (in-wave order)
    char* pw = pbase + l16 * 144 + quad * 8;
    char* pr = pbase + l16 * 144 + quad * 16;

    const unsigned short* gK = Kb + headoff;
    const unsigned short* gV = Vt2 + (size_t)nh * (32 * 4096);
    const unsigned long long* mbase = mb + (size_t)n * (SEQ * SEQ / 64)
                                         + (size_t)(q0 + l16) * (SEQ / 64);

    // all-ones bf16 A-fragment for row sums
    u16x8 ou;
#pragma unroll
    for (int jj = 0; jj < 8; ++jj) ou[jj] = 0x3F80;
    bf16x8 ones = __builtin_bit_cast(bf16x8, ou);

    f32x4 o[2][4] = {{{0,0,0,0},{0,0,0,0},{0,0,0,0},{0,0,0,0}},
                     {{0,0,0,0},{0,0,0,0},{0,0,0,0},{0,0,0,0}}};
    f32x4 lacc[2] = {{0,0,0,0},{0,0,0,0}};
    int qsh = quad * 4;

    int kb0   = SPLIT ? half * (SEQ / 2) : 0;
    int kbend = SPLIT ? kb0 + (SEQ / 2) : SEQ;

    // ---- prologue: stage K_0 -> buf0, V_0 -> Vbuf --------------------------
    {
        const char* sK = (const char*)(gK + (size_t)kb0 * 64) + stoff;
        const char* sV = (const char*)(gV + (size_t)(kb0 >> 6) * 4096) + stoff;
#pragma unroll
        for (int i2 = 0; i2 < 2; ++i2) {
            int c = wave * 2 + i2;
            GLOAD_LDS(sK + c * 1024, smem + c * 1024);
            GLOAD_LDS(sV + c * 1024, smem + 16384 + c * 1024);
        }
    }

    int par = 0;
    for (int kb = kb0; kb < kbend; kb += 64) {
        int kbn = (kb + 64) & (SEQ - 1);   // wrapped next tile (harmless at end)
        __syncthreads();   // (a) K_i, V_i visible; drains long-lead prefetches
        // ---- prefetch K_{i+1} into the other K buffer ----------------------
        {
            const char* sK = (const char*)(gK + (size_t)kbn * 64) + stoff;
            char* dK = smem + (par ^ 1) * 8192;
#pragma unroll
            for (int i2 = 0; i2 < 2; ++i2) {
                int c = wave * 2 + i2;
                GLOAD_LDS(sK + c * 1024, dK + c * 1024);
            }
        }
        // mask rows (L2-hot), pre-shifted by quad
        unsigned long long m64[2];
#pragma unroll
        for (int t = 0; t < 2; ++t)
            m64[t] = mbase[(size_t)(t * 16) * (SEQ / 64) + (kb >> 6)] >> qsh;

        // ---- K fragments (A-operand) from current buffer -------------------
        const char* kbuf = smem + par * 8192;
        bf16x8 kf[4][2];
#pragma unroll
        for (int kt = 0; kt < 4; ++kt) {
            kf[kt][0] = ldfrag(kbuf + aK0 + kt * 2048);
            kf[kt][1] = ldfrag(kbuf + (aK0 ^ 64) + kt * 2048);
        }
        // ---- per q-subtile: S^T=K*Q^T, mask+exp, P round-trip, sums, PV ----
#pragma unroll
        for (int t = 0; t < 2; ++t) {
            f32x4 c[4];
#pragma unroll
            for (int kt = 0; kt < 4; ++kt) {
                f32x4 cc = {0.f, 0.f, 0.f, 0.f};
                cc = mfma16(kf[kt][0], qf[t][0], cc);
                cc = mfma16(kf[kt][1], qf[t][1], cc);
                c[kt] = cc;   // c[kt][r]: key = kb+kt*16+quad*4+r, q = q0+t*16+l16
            }
            unsigned mlo = (unsigned)m64[t];
            unsigned mhi = (unsigned)(m64[t] >> 32);
#pragma unroll
            for (int kt = 0; kt < 4; ++kt) {
                unsigned mw = (kt & 2) ? mhi : mlo;
                int bs = (kt & 1) ? 16 : 0;
                float p0 = ((mw >> (bs + 0)) & 1u) ? __builtin_exp2f(c[kt][0]) : 0.f;
                float p1 = ((mw >> (bs + 1)) & 1u) ? __builtin_exp2f(c[kt][1]) : 0.f;
                float p2 = ((mw >> (bs + 2)) & 1u) ? __builtin_exp2f(c[kt][2]) : 0.f;
                float p3 = ((mw >> (bs + 3)) & 1u) ? __builtin_exp2f(c[kt][3]) : 0.f;
                uint2 dw = { packbf(p0, p1), packbf(p2, p3) };
                *(uint2*)(pw + kt * 32) = dw;
            }
            // P^T B-fragments (in-wave write->read ordering via DS pipe)
            bf16x8 pb0 = ldfrag(pr);
            bf16x8 pb1 = ldfrag(pr + 64);
            // row sums on the matrix pipe (quad-uniform result)
            lacc[t] = mfma16(ones, pb0, lacc[t]);
            lacc[t] = mfma16(ones, pb1, lacc[t]);
            // O^T = V^T * P^T
#pragma unroll
            for (int sl = 0; sl < 4; ++sl) {
                o[t][sl] = mfma16(ldfrag(smem + aV  + sl * 2048), pb0, o[t][sl]);
                o[t][sl] = mfma16(ldfrag(smem + aVx + sl * 2048), pb1, o[t][sl]);
            }
        }
        __syncthreads();   // (b) PV reads done; drains K_{i+1} (~0.7-iter lead)
        // ---- prefetch V_{i+1} (arrives by next barrier (a)) ----------------
        {
            const char* sV = (const char*)(gV + (size_t)(kbn >> 6) * 4096) + stoff;
#pragma unroll
            for (int i2 = 0; i2 < 2; ++i2) {
                int c = wave * 2 + i2;
                GLOAD_LDS(sV + c * 1024, smem + 16384 + c * 1024);
            }
        }
        par ^= 1;
    }

    // ---- epilogue: o[t][sl][r] = O[q=q0+t*16+l16][d=sl*16+quad*4+r] --------
#pragma unroll
    for (int t = 0; t < 2; ++t) {
        float s = lacc[t][0];               // row-sum, uniform across quads
        int q = q0 + t * 16 + l16;
        if (SPLIT) {
            size_t qg = (size_t)nh * SEQ + q;
            if (quad == 0) Ls[(size_t)half * 65536 + qg] = s;
            float* op = Of + ((size_t)half * 65536 + qg) * 64 + qsh;
#pragma unroll
            for (int sl = 0; sl < 4; ++sl) {
                float4 v = { o[t][sl][0], o[t][sl][1], o[t][sl][2], o[t][sl][3] };
                *(float4*)(op + sl * 16) = v;
            }
        } else {
            float rinv = 1.0f / s;
            unsigned short* op = Ab + (((size_t)(n * SEQ + q)) * HEADS + h) * HD + qsh;
#pragma unroll
            for (int sl = 0; sl < 4; ++sl) {
                u16x4 u;
                u[0] = f2bf(o[t][sl][0] * rinv);
                u[1] = f2bf(o[t][sl][1] * rinv);
                u[2] = f2bf(o[t][sl][2] * rinv);
                u[3] = f2bf(o[t][sl][3] * rinv);
                *(u16x4*)(op + sl * 16) = u;
            }
        }
    }
}

// ---------------- kernel: combine K-split halves ---------------------------
// Ab[(n*S+s)*H+h][d] = (O0+O1)/(l0+l1)
__global__ __launch_bounds__(256) void combine_kernel(
    const float* __restrict__ Of, const float* __restrict__ Ls,
    unsigned short* __restrict__ Ab)
{
    int idx = blockIdx.x * 256 + threadIdx.x;     // 1M threads, 4 floats each
    int q  = idx >> 4;                            // qglobal = nh*2048 + s
    int d0 = (idx & 15) * 4;
    const float4 o0 = *(const float4*)(Of + (size_t)q * 64 + d0);
    const float4 o1 = *(const float4*)(Of + 4194304 + (size_t)q * 64 + d0);
    float rl = 1.0f / (Ls[q] + Ls[65536 + q]);
    int n = q >> 15, h = (q >> 11) & 15, s = q & 2047;
    size_t ab = (((size_t)(n * SEQ + s)) * HEADS + h) * HD + d0;
    u16x4 u;
    u[0] = f2bf((o0.x + o1.x) * rl);
    u[1] = f2bf((o0.y + o1.y) * rl);
    u[2] = f2bf((o0.z + o1.z) * rl);
    u[3] = f2bf((o0.w + o1.w) * rl);
    *(u16x4*)(Ab + ab) = u;
}

// ---------------- kernel: out = Ab @ Wo^T + bo -----------------------------
// v2 FIXED: 128x64 tiles -> grid 512 (2 blocks/CU), A+B double-buffered
// (48 KB), ONE barrier per K-step, prefetch right after it (full-iter lead).
// Fragment offsets carry NO base; bases: A par*16384, B 32768 + par*8192;
// prefetch always targets parity^1.
__global__ __launch_bounds__(256) void out_gemm_kernel(
    const unsigned short* __restrict__ Ab, const unsigned short* __restrict__ Wob,
    const float* __restrict__ bo, float* __restrict__ out)
{
    // A par0 @0 (16K), A par1 @16384, B par0 @32768 (8K), B par1 @40960
    __shared__ __align__(16) char lds[49152];

    int tid = threadIdx.x;
    int wave = tid >> 6, lane = tid & 63;
    int quad = lane >> 4, l16 = lane & 15;
    int rt = blockIdx.x >> 4, ct = blockIdx.x & 15;
    int wr = wave >> 1, wc = wave & 1;

    int srow = lane >> 3, sslot = lane & 7;
    int stoff = srow * 2048 + (((sslot - srow) & 7) * 16);
    const char* gA = (const char*)Ab  + (size_t)rt * 128 * 2048 + stoff;
    const char* gB = (const char*)Wob + (size_t)ct * 64 * 2048 + stoff;

    int aA[4], aB[2];    // in-tile offsets, NO base
#pragma unroll
    for (int i = 0; i < 4; ++i) {
        int rowA = wr * 64 + i * 16 + l16;
        aA[i] = rowA * 128 + (((quad + rowA) & 7) * 16);
    }
#pragma unroll
    for (int sl = 0; sl < 2; ++sl) {
        int rowB = wc * 32 + sl * 16 + l16;
        aB[sl] = rowB * 128 + (((quad + rowB) & 7) * 16);
    }

    // ---- prologue: stage f=0 into parity 0 ---------------------------------
#pragma unroll
    for (int i = 0; i < 4; ++i) {
        int c = wave * 4 + i;                      // A: 16 chunks of 8 rows
        GLOAD_LDS(gA + (size_t)c * 16384, lds + c * 1024);
    }
#pragma unroll
    for (int i = 0; i < 2; ++i) {
        int c = wave * 2 + i;                      // B: 8 chunks
        GLOAD_LDS(gB + (size_t)c * 16384, lds + 32768 + c * 1024);
    }

    f32x4 acc[4][2] = {};
    int par = 0;
    for (int f = 0; f < ED; f += 64) {
        int fn = (f + 64) & (ED - 1);              // wrapped (harmless at end)
        __syncthreads();   // tiles(par) visible; prefetches have full-iter lead
        // ---- prefetch next K-slab into parity^1 ----------------------------
        {
            int pA = (par ^ 1) * 16384;
            int pB = 32768 + (par ^ 1) * 8192;
#pragma unroll
            for (int i = 0; i < 4; ++i) {
                int c = wave * 4 + i;
                GLOAD_LDS(gA + (size_t)c * 16384 + fn * 2, lds + pA + c * 1024);
            }
#pragma unroll
            for (int i = 0; i < 2; ++i) {
                int c = wave * 2 + i;
                GLOAD_LDS(gB + (size_t)c * 16384 + fn * 2, lds + pB + c * 1024);
            }
        }
        int bA = par * 16384;
        int bB = 32768 + par * 8192;
#pragma unroll
        for (int kk = 0; kk < 2; ++kk) {
            int x = kk * 64;
            bf16x8 af[4], bfr[2];
#pragma unroll
            for (int i = 0; i < 4; ++i)    af[i]  = ldfrag(lds + bA + (aA[i] ^ x));
#pragma unroll
            for (int sl = 0; sl < 2; ++sl) bfr[sl] = ldfrag(lds + bB + (aB[sl] ^ x));
#pragma unroll
            for (int i = 0; i < 4; ++i)
#pragma unroll
                for (int sl = 0; sl < 2; ++sl)
                    acc[i][sl] = mfma16(af[i], bfr[sl], acc[i][sl]);
        }
        par ^= 1;
    }

    float bv[2];
#pragma unroll
    for (int sl = 0; sl < 2; ++sl)
        bv[sl] = bo[ct * 64 + wc * 32 + sl * 16 + l16];
#pragma unroll
    for (int i = 0; i < 4; ++i)
#pragma unroll
        for (int r = 0; r < 4; ++r) {
            int row = rt * 128 + wr * 64 + i * 16 + quad * 4 + r;
#pragma unroll
            for (int sl = 0; sl < 2; ++sl) {
                int e = ct * 64 + wc * 32 + sl * 16 + l16;
                out[(size_t)row * ED + e] = acc[i][sl][r] + bv[sl];
            }
        }
}

// ---------------- launcher -------------------------------------------------
extern "C" void kernel_launch(void* const* d_in, const int* in_sizes, int n_in,
                              void* d_out, int out_size, void* d_ws, size_t ws_size,
                              hipStream_t stream)
{
    const float* values = (const float*)d_in[0];
    const float* keys   = (const float*)d_in[1];
    const float* query  = (const float*)d_in[2];
    const int*   mask   = (const int*)d_in[3];
    const float* Wv     = (const float*)d_in[4];
    const float* Wk     = (const float*)d_in[5];
    const float* Wq     = (const float*)d_in[6];
    const float* Wo     = (const float*)d_in[7];
    const float* bo     = (const float*)d_in[8];
    float* out = (float*)d_out;

    char* w = (char*)d_ws;
    unsigned short* Qb  = (unsigned short*)(w);              //  8 MB
    unsigned short* Kb  = (unsigned short*)(w +  8388608);   //  8 MB
    unsigned short* Vt  = (unsigned short*)(w + 16777216);   //  8 MB tiled V
    unsigned short* Ab  = (unsigned short*)(w + 25165824);   //  8 MB
    unsigned long long* Mb = (unsigned long long*)(w + 33554432); // 1 MB
    unsigned short* Wob = (unsigned short*)(w + 34603008);   //  2 MB
    float* Of = (float*)(w + 36700160);                      // 33.5 MB f32 (split)
    float* Ls = (float*)(w + 70254592);                      // 0.5 MB f32 (split)

    bool split = ws_size >= 70778880ULL;

    prep_kernel<<<NB * SEQ * SEQ / 256 + ED * ED / 1024, 256, 0, stream>>>(mask, Mb, Wo, Wob);
    proj_kernel<<<3 * HEADS * 64, 256, 0, stream>>>(query, keys, values, Wq, Wk, Wv, Qb, Kb, Vt);
    if (split) {
        attn_kernel<1><<<1024, 256, 0, stream>>>(Qb, Kb, Vt, Mb, Ab, Of, Ls);
        combine_kernel<<<4096, 256, 0, stream>>>(Of, Ls, Ab);
    } else {
        attn_kernel<0><<<512, 256, 0, stream>>>(Qb, Kb, Vt, Mb, Ab, Of, Ls);
    }
    out_gemm_kernel<<<512, 256, 0, stream>>>(Ab, Wob, bo, out);
}

// Round 11
// 234.464 us; speedup vs baseline: 1.1832x; 1.0404x over previous
//
#include <hip/hip_runtime.h>
#include <hip/hip_bf16.h>

// Problem constants
#define NB 2
#define SEQ 2048
#define HEADS 16
#define HD 64
#define ED 1024

typedef __bf16 bf16x8 __attribute__((ext_vector_type(8)));
typedef float f32x4 __attribute__((ext_vector_type(4)));
typedef unsigned short u16x8 __attribute__((ext_vector_type(8)));
typedef unsigned short u16x4 __attribute__((ext_vector_type(4)));

#if __has_builtin(__builtin_amdgcn_exp2f)
#define EXP2(x) __builtin_amdgcn_exp2f(x)   // raw v_exp_f32 (no denorm guard seq)
#else
#define EXP2(x) __builtin_exp2f(x)
#endif

__device__ __forceinline__ unsigned short f2bf(float f) {
    unsigned u = __builtin_bit_cast(unsigned, f);
    u += 0x7fffu + ((u >> 16) & 1u);   // RNE
    return (unsigned short)(u >> 16);
}

__device__ __forceinline__ bf16x8 cvt8(const float* __restrict__ p) {
    const float4* p4 = (const float4*)p;
    float4 a = p4[0], b = p4[1];
    u16x8 u;
    u[0] = f2bf(a.x); u[1] = f2bf(a.y); u[2] = f2bf(a.z); u[3] = f2bf(a.w);
    u[4] = f2bf(b.x); u[5] = f2bf(b.y); u[6] = f2bf(b.z); u[7] = f2bf(b.w);
    return __builtin_bit_cast(bf16x8, u);
}

__device__ __forceinline__ bf16x8 ldfrag(const void* p) {
    uint4 v = *(const uint4*)p;
    return __builtin_bit_cast(bf16x8, v);
}

__device__ __forceinline__ f32x4 mfma16(bf16x8 a, bf16x8 b, f32x4 c) {
    return __builtin_amdgcn_mfma_f32_16x16x32_bf16(a, b, c, 0, 0, 0);
}

// pack two positive f32 into bf16 pair (round-half-up): 2 adds + v_perm
__device__ __forceinline__ unsigned packbf(float lo, float hi) {
    unsigned a = __builtin_bit_cast(unsigned, hi) + 0x8000u;
    unsigned b = __builtin_bit_cast(unsigned, lo) + 0x8000u;
    return __builtin_amdgcn_perm(a, b, 0x07060302u);   // [hi16(a) : hi16(b)]
}

#define GLOAD_LDS(gp, lp) \
    __builtin_amdgcn_global_load_lds( \
        (const __attribute__((address_space(1))) unsigned int*)(gp), \
        (__attribute__((address_space(3))) unsigned int*)(lp), 16, 0, 0)

// softmax scale folded into Q at projection: (1/sqrt(1024)) * log2(e)
#define QSCALE 0.04508422f

// ---------------- kernel: QKV projections + mask->bits + Wo->bf16 ----------
// bid < 3072: proj (heavy, dispatched first).
// 3072..35839: mask bit-pack. 35840..36863: Wo convert.
// Q,K stored [n][h][s][64] bf16 (Q pre-scaled by QSCALE);
// V stored tiled [n][h][s/64][d][64] bf16.
__global__ __launch_bounds__(256) void proj_prep_kernel(
    const float* __restrict__ qin, const float* __restrict__ kin, const float* __restrict__ vin,
    const float* __restrict__ Wq, const float* __restrict__ Wk, const float* __restrict__ Wv,
    unsigned short* __restrict__ Qb, unsigned short* __restrict__ Kb,
    unsigned short* __restrict__ Vt,
    const int* __restrict__ mask, unsigned long long* __restrict__ bits,
    const float* __restrict__ Wo, unsigned short* __restrict__ Wob)
{
    __shared__ __align__(16) char tile[64 * 144];   // 64 rows x 144B (128B data + pad)

    int bid = blockIdx.x;
    if (bid >= 3072) {
        int b2 = bid - 3072;
        if (b2 < NB * SEQ * SEQ / 256) {
            size_t i = (size_t)b2 * 256 + threadIdx.x;
            int m = mask[i];
            unsigned long long b = __ballot(m != 0);
            if ((threadIdx.x & 63) == 0) bits[i >> 6] = b;
        } else {
            size_t i = ((size_t)(b2 - NB * SEQ * SEQ / 256) * 256 + threadIdx.x) * 4;
            float4 v = *(const float4*)(Wo + i);
            u16x4 u;
            u[0] = f2bf(v.x); u[1] = f2bf(v.y); u[2] = f2bf(v.z); u[3] = f2bf(v.w);
            *(u16x4*)(Wob + i) = u;
        }
        return;
    }

    int t3  = bid >> 10;
    int rem = bid & 1023;
    int h   = rem >> 6;
    int rt  = rem & 63;
    int wave = threadIdx.x >> 6, lane = threadIdx.x & 63;
    int quad = lane >> 4, l16 = lane & 15;

    const float* in = (t3 == 0) ? qin : ((t3 == 1) ? kin : vin);
    const float* W  = (t3 == 0) ? Wq  : ((t3 == 1) ? Wk  : Wv);

    int r0 = rt * 64 + wave * 16;   // global token row base for this wave

    bf16x8 bf0[4], bf1[4];
#pragma unroll
    for (int sl = 0; sl < 4; ++sl) {
        const float* wrow = W + (sl * 16 + l16) * 64;
        bf0[sl] = cvt8(wrow + quad * 8);
        bf1[sl] = cvt8(wrow + 32 + quad * 8);
    }
    const float* xrow = in + (size_t)(r0 + l16) * ED + h * 64;
    bf16x8 af0 = cvt8(xrow + quad * 8);
    bf16x8 af1 = cvt8(xrow + 32 + quad * 8);

    f32x4 acc[4];
#pragma unroll
    for (int sl = 0; sl < 4; ++sl) {
        f32x4 c = {0.f, 0.f, 0.f, 0.f};
        c = mfma16(af0, bf0[sl], c);
        c = mfma16(af1, bf1[sl], c);
        acc[sl] = c;
    }
    float sc = (t3 == 0) ? QSCALE : 1.0f;

    size_t nh = (size_t)((r0 >> 11) * HEADS + h);   // 64-row tile never straddles n
    int rl = lane >> 3, cl = lane & 7;              // readback row-in-group / 16B slot

    if (t3 != 2) {
        // ---- Q/K: LDS tile [s_local][e], wave-private rows, no barrier -----
#pragma unroll
        for (int r = 0; r < 4; ++r) {
            int srow = wave * 16 + quad * 4 + r;
#pragma unroll
            for (int sl = 0; sl < 4; ++sl)
                *(unsigned short*)(tile + srow * 144 + (sl * 16 + l16) * 2) =
                    f2bf(acc[sl][r] * sc);
        }
        unsigned short* dst = (t3 == 0) ? Qb : Kb;
        int s0 = (r0 & 2047);                        // this wave's first token row
#pragma unroll
        for (int g = 0; g < 2; ++g) {
            int lrow = wave * 16 + g * 8 + rl;
            uint4 v = *(const uint4*)(tile + lrow * 144 + cl * 16);
            *(uint4*)(dst + (nh * SEQ + (s0 & ~15) + g * 8 + rl) * HD + cl * 8) = v;
        }
    } else {
        // ---- V: LDS tile [e][s_local] (transpose), barrier across waves ----
#pragma unroll
        for (int r = 0; r < 4; ++r) {
            int srow = wave * 16 + quad * 4 + r;
#pragma unroll
            for (int sl = 0; sl < 4; ++sl)
                *(unsigned short*)(tile + (sl * 16 + l16) * 144 + srow * 2) =
                    f2bf(acc[sl][r]);
        }
        __syncthreads();
        int s_tile = rt & 31;
#pragma unroll
        for (int g = 0; g < 2; ++g) {
            int erow = wave * 16 + g * 8 + rl;
            uint4 v = *(const uint4*)(tile + erow * 144 + cl * 16);
            *(uint4*)(Vt + ((nh * 32 + s_tile) * 64 + erow) * 64 + cl * 8) = v;
        }
    }
}

// ---------------- kernel: flash attention (R7 two-barrier pipeline) --------
// 256 threads = 4 waves x 32 queries = 128 q / block.
// K double-buffered, V single-buffered; K prefetch after barrier (a), V
// prefetch after barrier (b) -> every staging load has >=0.7-iter lead.
// S^T scheme (A=K, B=Q); P round-trip via per-wave LDS tile; row-sums via
// all-ones MFMA (quad-uniform -> no shuffle reduction).
// exp via raw v_exp_f32 (__builtin_amdgcn_exp2f) -- no denorm-guard sequence.
// SPLIT=1: grid 1024 (2 k-halves), partial f32 O + lsum out; else grid 512.
template <int SPLIT>
__global__ __launch_bounds__(256, 4) void attn_kernel(
    const unsigned short* __restrict__ Qb, const unsigned short* __restrict__ Kb,
    const unsigned short* __restrict__ Vt2, const unsigned long long* __restrict__ mb,
    unsigned short* __restrict__ Ab, float* __restrict__ Of, float* __restrict__ Ls)
{
    // K buf0 @0, K buf1 @8192, V @16384, P @24576 + wave*2304
    __shared__ __align__(16) char smem[24576 + 4 * 2304];

    int tid = threadIdx.x;
    int wave = tid >> 6, lane = tid & 63;
    int quad = lane >> 4, l16 = lane & 15;

    // XCD swizzle: 4 consecutive nh per XCD -> K/V resident in its L2
    int b   = blockIdx.x;
    int xcd = b & 7;
    int j   = b >> 3;
    int nh, qb, half;
    if (SPLIT) { nh = xcd * 4 + (j >> 5); int r = j & 31; qb = r >> 1; half = r & 1; }
    else       { nh = xcd * 4 + (j >> 4); qb = j & 15; half = 0; }
    int n = nh >> 4, h = nh & 15;
    int q0 = qb * 128 + wave * 32;          // this wave's 32 queries

    size_t headoff = (size_t)nh * SEQ * HD;
    bf16x8 qf[2][2];                         // B-operand
#pragma unroll
    for (int t = 0; t < 2; ++t) {
        const unsigned short* qrow = Qb + headoff + (size_t)(q0 + t * 16 + l16) * HD;
        qf[t][0] = ldfrag(qrow + quad * 8);
        qf[t][1] = ldfrag(qrow + 32 + quad * 8);
    }

    // staging: per-lane source offset (bytes) with rotation ((slot - row)&7)
    int srow = lane >> 3, sslot = lane & 7;
    int stoff = srow * 128 + (((sslot - srow) & 7) * 16);

    // ds read address registers (bytes, loop-invariant)
    int rotA = ((quad + l16) & 7) * 16;
    int aK0 = l16 * 128 + rotA;           // + par*8192 + kt*2048 ; ^64 high half
    int aV  = 16384 + l16 * 128 + rotA;   // + sl*2048 ; ^64 key high half
    int aVx = aV ^ 64;
    char* pbase = smem + 24576 + wave * 2304;   // shared across t (in-wave order)
    char* pw = pbase + l16 * 144 + quad * 8;
    char* pr = pbase + l16 * 144 + quad * 16;

    const unsigned short* gK = Kb + headoff;
    const unsigned short* gV = Vt2 + (size_t)nh * (32 * 4096);
    const unsigned long long* mbase = mb + (size_t)n * (SEQ * SEQ / 64)
                                         + (size_t)(q0 + l16) * (SEQ / 64);

    // all-ones bf16 A-fragment for row sums
    u16x8 ou;
#pragma unroll
    for (int jj = 0; jj < 8; ++jj) ou[jj] = 0x3F80;
    bf16x8 ones = __builtin_bit_cast(bf16x8, ou);

    f32x4 o[2][4] = {{{0,0,0,0},{0,0,0,0},{0,0,0,0},{0,0,0,0}},
                     {{0,0,0,0},{0,0,0,0},{0,0,0,0},{0,0,0,0}}};
    f32x4 lacc[2] = {{0,0,0,0},{0,0,0,0}};
    int qsh = quad * 4;

    int kb0   = SPLIT ? half * (SEQ / 2) : 0;
    int kbend = SPLIT ? kb0 + (SEQ / 2) : SEQ;

    // ---- prologue: stage K_0 -> buf0, V_0 -> Vbuf --------------------------
    {
        const char* sK = (const char*)(gK + (size_t)kb0 * 64) + stoff;
        const char* sV = (const char*)(gV + (size_t)(kb0 >> 6) * 4096) + stoff;
#pragma unroll
        for (int i2 = 0; i2 < 2; ++i2) {
            int c = wave * 2 + i2;
            GLOAD_LDS(sK + c * 1024, smem + c * 1024);
            GLOAD_LDS(sV + c * 1024, smem + 16384 + c * 1024);
        }
    }

    int par = 0;
    for (int kb = kb0; kb < kbend; kb += 64) {
        int kbn = (kb + 64) & (SEQ - 1);   // wrapped next tile (harmless at end)
        __syncthreads();   // (a) K_i, V_i visible; drains long-lead prefetches
        // ---- prefetch K_{i+1} into the other K buffer ----------------------
        {
            const char* sK = (const char*)(gK + (size_t)kbn * 64) + stoff;
            char* dK = smem + (par ^ 1) * 8192;
#pragma unroll
            for (int i2 = 0; i2 < 2; ++i2) {
                int c = wave * 2 + i2;
                GLOAD_LDS(sK + c * 1024, dK + c * 1024);
            }
        }
        // mask rows (L2-hot), pre-shifted by quad
        unsigned long long m64[2];
#pragma unroll
        for (int t = 0; t < 2; ++t)
            m64[t] = mbase[(size_t)(t * 16) * (SEQ / 64) + (kb >> 6)] >> qsh;

        // ---- K fragments (A-operand) from current buffer -------------------
        const char* kbuf = smem + par * 8192;
        bf16x8 kf[4][2];
#pragma unroll
        for (int kt = 0; kt < 4; ++kt) {
            kf[kt][0] = ldfrag(kbuf + aK0 + kt * 2048);
            kf[kt][1] = ldfrag(kbuf + (aK0 ^ 64) + kt * 2048);
        }
        // ---- per q-subtile: S^T=K*Q^T, mask+exp, P round-trip, sums, PV ----
#pragma unroll
        for (int t = 0; t < 2; ++t) {
            f32x4 c[4];
#pragma unroll
            for (int kt = 0; kt < 4; ++kt) {
                f32x4 cc = {0.f, 0.f, 0.f, 0.f};
                cc = mfma16(kf[kt][0], qf[t][0], cc);
                cc = mfma16(kf[kt][1], qf[t][1], cc);
                c[kt] = cc;   // c[kt][r]: key = kb+kt*16+quad*4+r, q = q0+t*16+l16
            }
            unsigned mlo = (unsigned)m64[t];
            unsigned mhi = (unsigned)(m64[t] >> 32);
#pragma unroll
            for (int kt = 0; kt < 4; ++kt) {
                unsigned mw = (kt & 2) ? mhi : mlo;
                int bs = (kt & 1) ? 16 : 0;
                float p0 = ((mw >> (bs + 0)) & 1u) ? EXP2(c[kt][0]) : 0.f;
                float p1 = ((mw >> (bs + 1)) & 1u) ? EXP2(c[kt][1]) : 0.f;
                float p2 = ((mw >> (bs + 2)) & 1u) ? EXP2(c[kt][2]) : 0.f;
                float p3 = ((mw >> (bs + 3)) & 1u) ? EXP2(c[kt][3]) : 0.f;
                uint2 dw = { packbf(p0, p1), packbf(p2, p3) };
                *(uint2*)(pw + kt * 32) = dw;
            }
            // P^T B-fragments (in-wave write->read ordering via DS pipe)
            bf16x8 pb0 = ldfrag(pr);
            bf16x8 pb1 = ldfrag(pr + 64);
            // row sums on the matrix pipe (quad-uniform result)
            lacc[t] = mfma16(ones, pb0, lacc[t]);
            lacc[t] = mfma16(ones, pb1, lacc[t]);
            // O^T = V^T * P^T
#pragma unroll
            for (int sl = 0; sl < 4; ++sl) {
                o[t][sl] = mfma16(ldfrag(smem + aV  + sl * 2048), pb0, o[t][sl]);
                o[t][sl] = mfma16(ldfrag(smem + aVx + sl * 2048), pb1, o[t][sl]);
            }
        }
        __syncthreads();   // (b) PV reads done; drains K_{i+1} (~0.7-iter lead)
        // ---- prefetch V_{i+1} (arrives by next barrier (a)) ----------------
        {
            const char* sV = (const char*)(gV + (size_t)(kbn >> 6) * 4096) + stoff;
#pragma unroll
            for (int i2 = 0; i2 < 2; ++i2) {
                int c = wave * 2 + i2;
                GLOAD_LDS(sV + c * 1024, smem + 16384 + c * 1024);
            }
        }
        par ^= 1;
    }

    // ---- epilogue: o[t][sl][r] = O[q=q0+t*16+l16][d=sl*16+quad*4+r] --------
#pragma unroll
    for (int t = 0; t < 2; ++t) {
        float s = lacc[t][0];               // row-sum, uniform across quads
        int q = q0 + t * 16 + l16;
        if (SPLIT) {
            size_t qg = (size_t)nh * SEQ + q;
            if (quad == 0) Ls[(size_t)half * 65536 + qg] = s;
            float* op = Of + ((size_t)half * 65536 + qg) * 64 + qsh;
#pragma unroll
            for (int sl = 0; sl < 4; ++sl) {
                float4 v = { o[t][sl][0], o[t][sl][1], o[t][sl][2], o[t][sl][3] };
                *(float4*)(op + sl * 16) = v;
            }
        } else {
            float rinv = 1.0f / s;
            unsigned short* op = Ab + (((size_t)(n * SEQ + q)) * HEADS + h) * HD + qsh;
#pragma unroll
            for (int sl = 0; sl < 4; ++sl) {
                u16x4 u;
                u[0] = f2bf(o[t][sl][0] * rinv);
                u[1] = f2bf(o[t][sl][1] * rinv);
                u[2] = f2bf(o[t][sl][2] * rinv);
                u[3] = f2bf(o[t][sl][3] * rinv);
                *(u16x4*)(op + sl * 16) = u;
            }
        }
    }
}

// ---------------- kernel: combine K-split halves ---------------------------
// Ab[(n*S+s)*H+h][d] = (O0+O1)/(l0+l1)
__global__ __launch_bounds__(256) void combine_kernel(
    const float* __restrict__ Of, const float* __restrict__ Ls,
    unsigned short* __restrict__ Ab)
{
    int idx = blockIdx.x * 256 + threadIdx.x;     // 1M threads, 4 floats each
    int q  = idx >> 4;                            // qglobal = nh*2048 + s
    int d0 = (idx & 15) * 4;
    const float4 o0 = *(const float4*)(Of + (size_t)q * 64 + d0);
    const float4 o1 = *(const float4*)(Of + 4194304 + (size_t)q * 64 + d0);
    float rl = 1.0f / (Ls[q] + Ls[65536 + q]);
    int n = q >> 15, h = (q >> 11) & 15, s = q & 2047;
    size_t ab = (((size_t)(n * SEQ + s)) * HEADS + h) * HD + d0;
    u16x4 u;
    u[0] = f2bf((o0.x + o1.x) * rl);
    u[1] = f2bf((o0.y + o1.y) * rl);
    u[2] = f2bf((o0.z + o1.z) * rl);
    u[3] = f2bf((o0.w + o1.w) * rl);
    *(u16x4*)(Ab + ab) = u;
}

// ---------------- kernel: out = Ab @ Wo^T + bo -----------------------------
// v2: 128x64 tiles -> grid 512 (2 blocks/CU), A+B double-buffered (48 KB),
// ONE barrier per K-step, prefetch right after it (full-iter lead).
// Fragment offsets carry NO base; bases: A par*16384, B 32768 + par*8192.
__global__ __launch_bounds__(256) void out_gemm_kernel(
    const unsigned short* __restrict__ Ab, const unsigned short* __restrict__ Wob,
    const float* __restrict__ bo, float* __restrict__ out)
{
    // A par0 @0 (16K), A par1 @16384, B par0 @32768 (8K), B par1 @40960
    __shared__ __align__(16) char lds[49152];

    int tid = threadIdx.x;
    int wave = tid >> 6, lane = tid & 63;
    int quad = lane >> 4, l16 = lane & 15;
    int rt = blockIdx.x >> 4, ct = blockIdx.x & 15;
    int wr = wave >> 1, wc = wave & 1;

    int srow = lane >> 3, sslot = lane & 7;
    int stoff = srow * 2048 + (((sslot - srow) & 7) * 16);
    const char* gA = (const char*)Ab  + (size_t)rt * 128 * 2048 + stoff;
    const char* gB = (const char*)Wob + (size_t)ct * 64 * 2048 + stoff;

    int aA[4], aB[2];    // in-tile offsets, NO base
#pragma unroll
    for (int i = 0; i < 4; ++i) {
        int rowA = wr * 64 + i * 16 + l16;
        aA[i] = rowA * 128 + (((quad + rowA) & 7) * 16);
    }
#pragma unroll
    for (int sl = 0; sl < 2; ++sl) {
        int rowB = wc * 32 + sl * 16 + l16;
        aB[sl] = rowB * 128 + (((quad + rowB) & 7) * 16);
    }

    // ---- prologue: stage f=0 into parity 0 ---------------------------------
#pragma unroll
    for (int i = 0; i < 4; ++i) {
        int c = wave * 4 + i;                      // A: 16 chunks of 8 rows
        GLOAD_LDS(gA + (size_t)c * 16384, lds + c * 1024);
    }
#pragma unroll
    for (int i = 0; i < 2; ++i) {
        int c = wave * 2 + i;                      // B: 8 chunks
        GLOAD_LDS(gB + (size_t)c * 16384, lds + 32768 + c * 1024);
    }

    f32x4 acc[4][2] = {};
    int par = 0;
    for (int f = 0; f < ED; f += 64) {
        int fn = (f + 64) & (ED - 1);              // wrapped (harmless at end)
        __syncthreads();   // tiles(par) visible; prefetches have full-iter lead
        // ---- prefetch next K-slab into parity^1 ----------------------------
        {
            int pA = (par ^ 1) * 16384;
            int pB = 32768 + (par ^ 1) * 8192;
#pragma unroll
            for (int i = 0; i < 4; ++i) {
                int c = wave * 4 + i;
                GLOAD_LDS(gA + (size_t)c * 16384 + fn * 2, lds + pA + c * 1024);
            }
#pragma unroll
            for (int i = 0; i < 2; ++i) {
                int c = wave * 2 + i;
                GLOAD_LDS(gB + (size_t)c * 16384 + fn * 2, lds + pB + c * 1024);
            }
        }
        int bA = par * 16384;
        int bB = 32768 + par * 8192;
#pragma unroll
        for (int kk = 0; kk < 2; ++kk) {
            int x = kk * 64;
            bf16x8 af[4], bfr[2];
#pragma unroll
            for (int i = 0; i < 4; ++i)    af[i]  = ldfrag(lds + bA + (aA[i] ^ x));
#pragma unroll
            for (int sl = 0; sl < 2; ++sl) bfr[sl] = ldfrag(lds + bB + (aB[sl] ^ x));
#pragma unroll
            for (int i = 0; i < 4; ++i)
#pragma unroll
                for (int sl = 0; sl < 2; ++sl)
                    acc[i][sl] = mfma16(af[i], bfr[sl], acc[i][sl]);
        }
        par ^= 1;
    }

    float bv[2];
#pragma unroll
    for (int sl = 0; sl < 2; ++sl)
        bv[sl] = bo[ct * 64 + wc * 32 + sl * 16 + l16];
#pragma unroll
    for (int i = 0; i < 4; ++i)
#pragma unroll
        for (int r = 0; r < 4; ++r) {
            int row = rt * 128 + wr * 64 + i * 16 + quad * 4 + r;
#pragma unroll
            for (int sl = 0; sl < 2; ++sl) {
                int e = ct * 64 + wc * 32 + sl * 16 + l16;
                out[(size_t)row * ED + e] = acc[i][sl][r] + bv[sl];
            }
        }
}

// ---------------- launcher -------------------------------------------------
extern "C" void kernel_launch(void* const* d_in, const int* in_sizes, int n_in,
                              void* d_out, int out_size, void* d_ws, size_t ws_size,
                              hipStream_t stream)
{
    const float* values = (const float*)d_in[0];
    const float* keys   = (const float*)d_in[1];
    const float* query  = (const float*)d_in[2];
    const int*   mask   = (const int*)d_in[3];
    const float* Wv     = (const float*)d_in[4];
    const float* Wk     = (const float*)d_in[5];
    const float* Wq     = (const float*)d_in[6];
    const float* Wo     = (const float*)d_in[7];
    const float* bo     = (const float*)d_in[8];
    float* out = (float*)d_out;

    char* w = (char*)d_ws;
    unsigned short* Qb  = (unsigned short*)(w);              //  8 MB
    unsigned short* Kb  = (unsigned short*)(w +  8388608);   //  8 MB
    unsigned short* Vt  = (unsigned short*)(w + 16777216);   //  8 MB tiled V
    unsigned short* Ab  = (unsigned short*)(w + 25165824);   //  8 MB
    unsigned long long* Mb = (unsigned long long*)(w + 33554432); // 1 MB
    unsigned short* Wob = (unsigned short*)(w + 34603008);   //  2 MB
    float* Of = (float*)(w + 36700160);                      // 33.5 MB f32 (split)
    float* Ls = (float*)(w + 70254592);                      // 0.5 MB f32 (split)

    bool split = ws_size >= 70778880ULL;

    proj_prep_kernel<<<3072 + NB * SEQ * SEQ / 256 + ED * ED / 1024, 256, 0, stream>>>(
        query, keys, values, Wq, Wk, Wv, Qb, Kb, Vt, mask, Mb, Wo, Wob);
    if (split) {
        attn_kernel<1><<<1024, 256, 0, stream>>>(Qb, Kb, Vt, Mb, Ab, Of, Ls);
        combine_kernel<<<4096, 256, 0, stream>>>(Of, Ls, Ab);
    } else {
        attn_kernel<0><<<512, 256, 0, stream>>>(Qb, Kb, Vt, Mb, Ab, Of, Ls);
    }
    out_gemm_kernel<<<512, 256, 0, stream>>>(Ab, Wob, bo, out);
}

// Round 12
// 231.360 us; speedup vs baseline: 1.1991x; 1.0134x over previous
//
#include <hip/hip_runtime.h>
#include <hip/hip_bf16.h>

// Problem constants
#define NB 2
#define SEQ 2048
#define HEADS 16
#define HD 64
#define ED 1024

typedef __bf16 bf16x8 __attribute__((ext_vector_type(8)));
typedef float f32x4 __attribute__((ext_vector_type(4)));
typedef unsigned short u16x8 __attribute__((ext_vector_type(8)));
typedef unsigned short u16x4 __attribute__((ext_vector_type(4)));

#if __has_builtin(__builtin_amdgcn_exp2f)
#define EXP2(x) __builtin_amdgcn_exp2f(x)   // raw v_exp_f32 (no denorm guard seq)
#else
#define EXP2(x) __builtin_exp2f(x)
#endif

__device__ __forceinline__ unsigned short f2bf(float f) {
    unsigned u = __builtin_bit_cast(unsigned, f);
    u += 0x7fffu + ((u >> 16) & 1u);   // RNE
    return (unsigned short)(u >> 16);
}

__device__ __forceinline__ bf16x8 cvt8(const float* __restrict__ p) {
    const float4* p4 = (const float4*)p;
    float4 a = p4[0], b = p4[1];
    u16x8 u;
    u[0] = f2bf(a.x); u[1] = f2bf(a.y); u[2] = f2bf(a.z); u[3] = f2bf(a.w);
    u[4] = f2bf(b.x); u[5] = f2bf(b.y); u[6] = f2bf(b.z); u[7] = f2bf(b.w);
    return __builtin_bit_cast(bf16x8, u);
}

__device__ __forceinline__ bf16x8 ldfrag(const void* p) {
    uint4 v = *(const uint4*)p;
    return __builtin_bit_cast(bf16x8, v);
}

__device__ __forceinline__ f32x4 mfma16(bf16x8 a, bf16x8 b, f32x4 c) {
    return __builtin_amdgcn_mfma_f32_16x16x32_bf16(a, b, c, 0, 0, 0);
}

// pack two positive f32 into bf16 pair (round-half-up): 2 adds + v_perm
__device__ __forceinline__ unsigned packbf(float lo, float hi) {
    unsigned a = __builtin_bit_cast(unsigned, hi) + 0x8000u;
    unsigned b = __builtin_bit_cast(unsigned, lo) + 0x8000u;
    return __builtin_amdgcn_perm(a, b, 0x07060302u);   // [hi16(a) : hi16(b)]
}

#define GLOAD_LDS(gp, lp) \
    __builtin_amdgcn_global_load_lds( \
        (const __attribute__((address_space(1))) unsigned int*)(gp), \
        (__attribute__((address_space(3))) unsigned int*)(lp), 16, 0, 0)

// softmax scale folded into Q at projection: (1/sqrt(1024)) * log2(e)
#define QSCALE 0.04508422f

// ---------------- kernel: QKV projections + mask->bits + Wo->bf16 ----------
// bid < 3072: proj (heavy, dispatched first).
// 3072..35839: mask bit-pack. 35840..36863: Wo convert.
// Q,K stored [n][h][s][64] bf16 (Q pre-scaled by QSCALE);
// V stored tiled [n][h][s/64][d][64] bf16.
__global__ __launch_bounds__(256) void proj_prep_kernel(
    const float* __restrict__ qin, const float* __restrict__ kin, const float* __restrict__ vin,
    const float* __restrict__ Wq, const float* __restrict__ Wk, const float* __restrict__ Wv,
    unsigned short* __restrict__ Qb, unsigned short* __restrict__ Kb,
    unsigned short* __restrict__ Vt,
    const int* __restrict__ mask, unsigned long long* __restrict__ bits,
    const float* __restrict__ Wo, unsigned short* __restrict__ Wob)
{
    __shared__ __align__(16) char tile[64 * 144];   // 64 rows x 144B (128B data + pad)

    int bid = blockIdx.x;
    if (bid >= 3072) {
        int b2 = bid - 3072;
        if (b2 < NB * SEQ * SEQ / 256) {
            size_t i = (size_t)b2 * 256 + threadIdx.x;
            int m = mask[i];
            unsigned long long b = __ballot(m != 0);
            if ((threadIdx.x & 63) == 0) bits[i >> 6] = b;
        } else {
            size_t i = ((size_t)(b2 - NB * SEQ * SEQ / 256) * 256 + threadIdx.x) * 4;
            float4 v = *(const float4*)(Wo + i);
            u16x4 u;
            u[0] = f2bf(v.x); u[1] = f2bf(v.y); u[2] = f2bf(v.z); u[3] = f2bf(v.w);
            *(u16x4*)(Wob + i) = u;
        }
        return;
    }

    int t3  = bid >> 10;
    int rem = bid & 1023;
    int h   = rem >> 6;
    int rt  = rem & 63;
    int wave = threadIdx.x >> 6, lane = threadIdx.x & 63;
    int quad = lane >> 4, l16 = lane & 15;

    const float* in = (t3 == 0) ? qin : ((t3 == 1) ? kin : vin);
    const float* W  = (t3 == 0) ? Wq  : ((t3 == 1) ? Wk  : Wv);

    int r0 = rt * 64 + wave * 16;   // global token row base for this wave

    bf16x8 bf0[4], bf1[4];
#pragma unroll
    for (int sl = 0; sl < 4; ++sl) {
        const float* wrow = W + (sl * 16 + l16) * 64;
        bf0[sl] = cvt8(wrow + quad * 8);
        bf1[sl] = cvt8(wrow + 32 + quad * 8);
    }
    const float* xrow = in + (size_t)(r0 + l16) * ED + h * 64;
    bf16x8 af0 = cvt8(xrow + quad * 8);
    bf16x8 af1 = cvt8(xrow + 32 + quad * 8);

    f32x4 acc[4];
#pragma unroll
    for (int sl = 0; sl < 4; ++sl) {
        f32x4 c = {0.f, 0.f, 0.f, 0.f};
        c = mfma16(af0, bf0[sl], c);
        c = mfma16(af1, bf1[sl], c);
        acc[sl] = c;
    }
    float sc = (t3 == 0) ? QSCALE : 1.0f;

    size_t nh = (size_t)((r0 >> 11) * HEADS + h);   // 64-row tile never straddles n
    int rl = lane >> 3, cl = lane & 7;              // readback row-in-group / 16B slot

    if (t3 != 2) {
        // ---- Q/K: LDS tile [s_local][e], wave-private rows, no barrier -----
#pragma unroll
        for (int r = 0; r < 4; ++r) {
            int srow = wave * 16 + quad * 4 + r;
#pragma unroll
            for (int sl = 0; sl < 4; ++sl)
                *(unsigned short*)(tile + srow * 144 + (sl * 16 + l16) * 2) =
                    f2bf(acc[sl][r] * sc);
        }
        unsigned short* dst = (t3 == 0) ? Qb : Kb;
        int s0 = (r0 & 2047);                        // this wave's first token row
#pragma unroll
        for (int g = 0; g < 2; ++g) {
            int lrow = wave * 16 + g * 8 + rl;
            uint4 v = *(const uint4*)(tile + lrow * 144 + cl * 16);
            *(uint4*)(dst + (nh * SEQ + (s0 & ~15) + g * 8 + rl) * HD + cl * 8) = v;
        }
    } else {
        // ---- V: LDS tile [e][s_local] (transpose), barrier across waves ----
#pragma unroll
        for (int r = 0; r < 4; ++r) {
            int srow = wave * 16 + quad * 4 + r;
#pragma unroll
            for (int sl = 0; sl < 4; ++sl)
                *(unsigned short*)(tile + (sl * 16 + l16) * 144 + srow * 2) =
                    f2bf(acc[sl][r]);
        }
        __syncthreads();
        int s_tile = rt & 31;
#pragma unroll
        for (int g = 0; g < 2; ++g) {
            int erow = wave * 16 + g * 8 + rl;
            uint4 v = *(const uint4*)(tile + erow * 144 + cl * 16);
            *(uint4*)(Vt + ((nh * 32 + s_tile) * 64 + erow) * 64 + cl * 8) = v;
        }
    }
}

// ---------------- kernel: flash attention, full-K, no split ----------------
// 256 threads = 4 waves x 16 queries = 64 q / block; grid = 32 nh x 32 qb
// = 1024 blocks -> 4 blocks/CU, 16 waves/CU (same occupancy as the old
// K-split config) with NO combine pass and NO partial-O traffic.
// K double-buffered, V single-buffered; K prefetch after barrier (a), V
// prefetch after barrier (b) -> every staging load has >=0.7-iter lead.
// S^T scheme (A=K, B=Q); P round-trip via per-wave LDS tile; row-sums via
// all-ones MFMA (quad-uniform); exp via raw v_exp_f32.
__global__ __launch_bounds__(256, 4) void attn_kernel(
    const unsigned short* __restrict__ Qb, const unsigned short* __restrict__ Kb,
    const unsigned short* __restrict__ Vt2, const unsigned long long* __restrict__ mb,
    unsigned short* __restrict__ Ab)
{
    // K buf0 @0, K buf1 @8192, V @16384, P @24576 + wave*2304
    __shared__ __align__(16) char smem[24576 + 4 * 2304];

    int tid = threadIdx.x;
    int wave = tid >> 6, lane = tid & 63;
    int quad = lane >> 4, l16 = lane & 15;

    // XCD swizzle: 4 consecutive nh per XCD -> K/V resident in its L2
    int b   = blockIdx.x;
    int xcd = b & 7;
    int j   = b >> 3;             // 0..127
    int nh  = xcd * 4 + (j >> 5);
    int qb  = j & 31;
    int n = nh >> 4, h = nh & 15;
    int q0 = qb * 64 + wave * 16;           // this wave's 16 queries

    size_t headoff = (size_t)nh * SEQ * HD;
    // Q fragments (B-operand)
    const unsigned short* qrow = Qb + headoff + (size_t)(q0 + l16) * HD;
    bf16x8 qf0 = ldfrag(qrow + quad * 8);
    bf16x8 qf1 = ldfrag(qrow + 32 + quad * 8);

    // staging: per-lane source offset (bytes) with rotation ((slot - row)&7)
    int srow = lane >> 3, sslot = lane & 7;
    int stoff = srow * 128 + (((sslot - srow) & 7) * 16);

    // ds read address registers (bytes, loop-invariant)
    int rotA = ((quad + l16) & 7) * 16;
    int aK0 = l16 * 128 + rotA;           // + par*8192 + kt*2048 ; ^64 high half
    int aV  = 16384 + l16 * 128 + rotA;   // + sl*2048 ; ^64 key high half
    int aVx = aV ^ 64;
    char* pbase = smem + 24576 + wave * 2304;
    char* pw = pbase + l16 * 144 + quad * 8;
    char* pr = pbase + l16 * 144 + quad * 16;

    const unsigned short* gK = Kb + headoff;
    const unsigned short* gV = Vt2 + (size_t)nh * (32 * 4096);
    const unsigned long long* mbase = mb + (size_t)n * (SEQ * SEQ / 64)
                                         + (size_t)(q0 + l16) * (SEQ / 64);

    // all-ones bf16 A-fragment for row sums
    u16x8 ou;
#pragma unroll
    for (int jj = 0; jj < 8; ++jj) ou[jj] = 0x3F80;
    bf16x8 ones = __builtin_bit_cast(bf16x8, ou);

    f32x4 o[4] = {{0,0,0,0},{0,0,0,0},{0,0,0,0},{0,0,0,0}};
    f32x4 lacc = {0,0,0,0};
    int qsh = quad * 4;

    // ---- prologue: stage K_0 -> buf0, V_0 -> Vbuf --------------------------
    {
        const char* sK = (const char*)gK + stoff;
        const char* sV = (const char*)gV + stoff;
#pragma unroll
        for (int i2 = 0; i2 < 2; ++i2) {
            int c = wave * 2 + i2;
            GLOAD_LDS(sK + c * 1024, smem + c * 1024);
            GLOAD_LDS(sV + c * 1024, smem + 16384 + c * 1024);
        }
    }

    int par = 0;
    for (int kb = 0; kb < SEQ; kb += 64) {
        int kbn = (kb + 64) & (SEQ - 1);   // wrapped next tile (harmless at end)
        __syncthreads();   // (a) K_i, V_i visible; drains long-lead prefetches
        // ---- prefetch K_{i+1} into the other K buffer ----------------------
        {
            const char* sK = (const char*)(gK + (size_t)kbn * 64) + stoff;
            char* dK = smem + (par ^ 1) * 8192;
#pragma unroll
            for (int i2 = 0; i2 < 2; ++i2) {
                int c = wave * 2 + i2;
                GLOAD_LDS(sK + c * 1024, dK + c * 1024);
            }
        }
        // mask row for this lane's query (L2-hot), pre-shifted by quad
        unsigned long long m64 = mbase[kb >> 6] >> qsh;

        // ---- K fragments (A-operand) from current buffer -------------------
        const char* kbuf = smem + par * 8192;
        bf16x8 kf[4][2];
#pragma unroll
        for (int kt = 0; kt < 4; ++kt) {
            kf[kt][0] = ldfrag(kbuf + aK0 + kt * 2048);
            kf[kt][1] = ldfrag(kbuf + (aK0 ^ 64) + kt * 2048);
        }
        // ---- S^T = K*Q^T ; mask+exp ; P round-trip ; row-sum ; PV ----------
        f32x4 c[4];
#pragma unroll
        for (int kt = 0; kt < 4; ++kt) {
            f32x4 cc = {0.f, 0.f, 0.f, 0.f};
            cc = mfma16(kf[kt][0], qf0, cc);
            cc = mfma16(kf[kt][1], qf1, cc);
            c[kt] = cc;   // c[kt][r]: key = kb+kt*16+quad*4+r, q = q0+l16
        }
        unsigned mlo = (unsigned)m64;
        unsigned mhi = (unsigned)(m64 >> 32);
#pragma unroll
        for (int kt = 0; kt < 4; ++kt) {
            unsigned mw = (kt & 2) ? mhi : mlo;
            int bs = (kt & 1) ? 16 : 0;
            float p0 = ((mw >> (bs + 0)) & 1u) ? EXP2(c[kt][0]) : 0.f;
            float p1 = ((mw >> (bs + 1)) & 1u) ? EXP2(c[kt][1]) : 0.f;
            float p2 = ((mw >> (bs + 2)) & 1u) ? EXP2(c[kt][2]) : 0.f;
            float p3 = ((mw >> (bs + 3)) & 1u) ? EXP2(c[kt][3]) : 0.f;
            uint2 dw = { packbf(p0, p1), packbf(p2, p3) };
            *(uint2*)(pw + kt * 32) = dw;
        }
        // P^T B-fragments (in-wave write->read ordering via DS pipe)
        bf16x8 pb0 = ldfrag(pr);
        bf16x8 pb1 = ldfrag(pr + 64);
        // row sums on the matrix pipe (quad-uniform result)
        lacc = mfma16(ones, pb0, lacc);
        lacc = mfma16(ones, pb1, lacc);
        // O^T = V^T * P^T
#pragma unroll
        for (int sl = 0; sl < 4; ++sl) {
            o[sl] = mfma16(ldfrag(smem + aV  + sl * 2048), pb0, o[sl]);
            o[sl] = mfma16(ldfrag(smem + aVx + sl * 2048), pb1, o[sl]);
        }
        __syncthreads();   // (b) PV reads done; drains K_{i+1} (~0.7-iter lead)
        // ---- prefetch V_{i+1} (arrives by next barrier (a)) ----------------
        {
            const char* sV = (const char*)(gV + (size_t)(kbn >> 6) * 4096) + stoff;
#pragma unroll
            for (int i2 = 0; i2 < 2; ++i2) {
                int c = wave * 2 + i2;
                GLOAD_LDS(sV + c * 1024, smem + 16384 + c * 1024);
            }
        }
        par ^= 1;
    }

    // ---- epilogue: o[sl][r] = O[q=q0+l16][d=sl*16+quad*4+r] ----------------
    {
        float rinv = 1.0f / lacc[0];        // row-sum, uniform across quads
        int q = q0 + l16;
        unsigned short* op = Ab + (((size_t)(n * SEQ + q)) * HEADS + h) * HD + qsh;
#pragma unroll
        for (int sl = 0; sl < 4; ++sl) {
            u16x4 u;
            u[0] = f2bf(o[sl][0] * rinv);
            u[1] = f2bf(o[sl][1] * rinv);
            u[2] = f2bf(o[sl][2] * rinv);
            u[3] = f2bf(o[sl][3] * rinv);
            *(u16x4*)(op + sl * 16) = u;
        }
    }
}

// ---------------- kernel: out = Ab @ Wo^T + bo -----------------------------
// v2: 128x64 tiles -> grid 512 (2 blocks/CU), A+B double-buffered (48 KB),
// ONE barrier per K-step, prefetch right after it (full-iter lead).
// Fragment offsets carry NO base; bases: A par*16384, B 32768 + par*8192.
__global__ __launch_bounds__(256) void out_gemm_kernel(
    const unsigned short* __restrict__ Ab, const unsigned short* __restrict__ Wob,
    const float* __restrict__ bo, float* __restrict__ out)
{
    // A par0 @0 (16K), A par1 @16384, B par0 @32768 (8K), B par1 @40960
    __shared__ __align__(16) char lds[49152];

    int tid = threadIdx.x;
    int wave = tid >> 6, lane = tid & 63;
    int quad = lane >> 4, l16 = lane & 15;
    int rt = blockIdx.x >> 4, ct = blockIdx.x & 15;
    int wr = wave >> 1, wc = wave & 1;

    int srow = lane >> 3, sslot = lane & 7;
    int stoff = srow * 2048 + (((sslot - srow) & 7) * 16);
    const char* gA = (const char*)Ab  + (size_t)rt * 128 * 2048 + stoff;
    const char* gB = (const char*)Wob + (size_t)ct * 64 * 2048 + stoff;

    int aA[4], aB[2];    // in-tile offsets, NO base
#pragma unroll
    for (int i = 0; i < 4; ++i) {
        int rowA = wr * 64 + i * 16 + l16;
        aA[i] = rowA * 128 + (((quad + rowA) & 7) * 16);
    }
#pragma unroll
    for (int sl = 0; sl < 2; ++sl) {
        int rowB = wc * 32 + sl * 16 + l16;
        aB[sl] = rowB * 128 + (((quad + rowB) & 7) * 16);
    }

    // ---- prologue: stage f=0 into parity 0 ---------------------------------
#pragma unroll
    for (int i = 0; i < 4; ++i) {
        int c = wave * 4 + i;                      // A: 16 chunks of 8 rows
        GLOAD_LDS(gA + (size_t)c * 16384, lds + c * 1024);
    }
#pragma unroll
    for (int i = 0; i < 2; ++i) {
        int c = wave * 2 + i;                      // B: 8 chunks
        GLOAD_LDS(gB + (size_t)c * 16384, lds + 32768 + c * 1024);
    }

    f32x4 acc[4][2] = {};
    int par = 0;
    for (int f = 0; f < ED; f += 64) {
        int fn = (f + 64) & (ED - 1);              // wrapped (harmless at end)
        __syncthreads();   // tiles(par) visible; prefetches have full-iter lead
        // ---- prefetch next K-slab into parity^1 ----------------------------
        {
            int pA = (par ^ 1) * 16384;
            int pB = 32768 + (par ^ 1) * 8192;
#pragma unroll
            for (int i = 0; i < 4; ++i) {
                int c = wave * 4 + i;
                GLOAD_LDS(gA + (size_t)c * 16384 + fn * 2, lds + pA + c * 1024);
            }
#pragma unroll
            for (int i = 0; i < 2; ++i) {
                int c = wave * 2 + i;
                GLOAD_LDS(gB + (size_t)c * 16384 + fn * 2, lds + pB + c * 1024);
            }
        }
        int bA = par * 16384;
        int bB = 32768 + par * 8192;
#pragma unroll
        for (int kk = 0; kk < 2; ++kk) {
            int x = kk * 64;
            bf16x8 af[4], bfr[2];
#pragma unroll
            for (int i = 0; i < 4; ++i)    af[i]  = ldfrag(lds + bA + (aA[i] ^ x));
#pragma unroll
            for (int sl = 0; sl < 2; ++sl) bfr[sl] = ldfrag(lds + bB + (aB[sl] ^ x));
#pragma unroll
            for (int i = 0; i < 4; ++i)
#pragma unroll
                for (int sl = 0; sl < 2; ++sl)
                    acc[i][sl] = mfma16(af[i], bfr[sl], acc[i][sl]);
        }
        par ^= 1;
    }

    float bv[2];
#pragma unroll
    for (int sl = 0; sl < 2; ++sl)
        bv[sl] = bo[ct * 64 + wc * 32 + sl * 16 + l16];
#pragma unroll
    for (int i = 0; i < 4; ++i)
#pragma unroll
        for (int r = 0; r < 4; ++r) {
            int row = rt * 128 + wr * 64 + i * 16 + quad * 4 + r;
#pragma unroll
            for (int sl = 0; sl < 2; ++sl) {
                int e = ct * 64 + wc * 32 + sl * 16 + l16;
                out[(size_t)row * ED + e] = acc[i][sl][r] + bv[sl];
            }
        }
}

// ---------------- launcher -------------------------------------------------
extern "C" void kernel_launch(void* const* d_in, const int* in_sizes, int n_in,
                              void* d_out, int out_size, void* d_ws, size_t ws_size,
                              hipStream_t stream)
{
    const float* values = (const float*)d_in[0];
    const float* keys   = (const float*)d_in[1];
    const float* query  = (const float*)d_in[2];
    const int*   mask   = (const int*)d_in[3];
    const float* Wv     = (const float*)d_in[4];
    const float* Wk     = (const float*)d_in[5];
    const float* Wq     = (const float*)d_in[6];
    const float* Wo     = (const float*)d_in[7];
    const float* bo     = (const float*)d_in[8];
    float* out = (float*)d_out;

    char* w = (char*)d_ws;
    unsigned short* Qb  = (unsigned short*)(w);              //  8 MB
    unsigned short* Kb  = (unsigned short*)(w +  8388608);   //  8 MB
    unsigned short* Vt  = (unsigned short*)(w + 16777216);   //  8 MB tiled V
    unsigned short* Ab  = (unsigned short*)(w + 25165824);   //  8 MB
    unsigned long long* Mb = (unsigned long long*)(w + 33554432); // 1 MB
    unsigned short* Wob = (unsigned short*)(w + 34603008);   //  2 MB

    proj_prep_kernel<<<3072 + NB * SEQ * SEQ / 256 + ED * ED / 1024, 256, 0, stream>>>(
        query, keys, values, Wq, Wk, Wv, Qb, Kb, Vt, mask, Mb, Wo, Wob);
    attn_kernel<<<1024, 256, 0, stream>>>(Qb, Kb, Vt, Mb, Ab);
    out_gemm_kernel<<<512, 256, 0, stream>>>(Ab, Wob, bo, out);
}